// Round 10
// baseline (208.820 us; speedup 1.0000x reference)
//
#include <hip/hip_runtime.h>

typedef float  f4    __attribute__((ext_vector_type(4)));
typedef float  f32x4 __attribute__((ext_vector_type(4)));
typedef short  s16x8 __attribute__((ext_vector_type(8)));
typedef unsigned int u32x4 __attribute__((ext_vector_type(4)));

#define L_SEQ 2048
#define D4    16
#define NC4   512
#define RAD   128
#define TI    64             // rows per block (4 waves x 16-row MFMA tiles)
#define NBH   48
#define NTIL  (L_SEQ / TI)   // 32
#define NBLK  (NBH * NTIL)   // 1536
#define KROWS (TI + 2*RAD)   // 320 staged K rows

// MFMA band + streamer kernel. Block = 256 thr (4 waves), 64 output rows.
//   stage K[i0-128, i0+192) as bf16 (swizzled 16B units) -> barrier ->
//   wave w MFMAs its 16-row tile over <=17 16-col tiles (2x mfma 16x16x32,
//   band-masked scalar C stores) -> all waves zero-stream the window
//   complement. Compute cost ~0 => every wave is effectively a streamer.
// A/B frag d-ordering consistency: both loaded with d = 8*(lane>>4)+elem
// (same mapping), so any hw k-permutation cancels in the dot product; C/D
// layout is the HW-verified col=lane&15, row=4*(lane>>4)+reg.

__device__ __forceinline__ unsigned bf16rne(float f) {
    unsigned u = __float_as_uint(f);
    return (u + 0x7FFFu + ((u >> 16) & 1u)) >> 16;   // round-to-nearest-even
}

__global__ __launch_bounds__(256, 4)
void band_mfma(const float* __restrict__ Qg, const float* __restrict__ Kg,
               float* __restrict__ outg)
{
    // K rows as 8 16B-units (8 bf16, d-ascending); slot = si*8 + (u ^ (si&7))
    // -> staging writes and 16-lane B-frag reads both conflict-free.
    __shared__ u32x4 sK[KROWS * 8];     // 40960 B -> 4 blocks/CU

    const int t  = threadIdx.x;
    const int id = blockIdx.x;
    // bijective XCD swizzle (NBLK % 8 == 0)
    const int swz = (id & 7) * (NBLK / 8) + (id >> 3);
    const int bh  = swz >> 5;
    const int i0  = (swz & (NTIL - 1)) * TI;

    const f4* __restrict__ K4 = reinterpret_cast<const f4*>(Kg) + (size_t)bh * L_SEQ * D4;
    const f4* __restrict__ Q4 = reinterpret_cast<const f4*>(Qg) + (size_t)bh * L_SEQ * D4;
    float* __restrict__ ob    = outg + (size_t)bh * L_SEQ * L_SEQ;

    const int kbase = i0 - RAD;

    // ---- stage K as bf16: 2560 units, 10 per thread
#pragma unroll 2
    for (int itr = 0; itr < 10; ++itr) {
        const int s  = itr * 256 + t;
        const int si = s >> 3, u = s & 7;
        int row = kbase + si;
        row = row < 0 ? 0 : (row > L_SEQ - 1 ? L_SEQ - 1 : row);  // clamp; never read (c-range guards)
        const f4 a = K4[(size_t)row * D4 + 2 * u];
        const f4 b = K4[(size_t)row * D4 + 2 * u + 1];
        u32x4 w;
        w.x = bf16rne(a.x) | (bf16rne(a.y) << 16);
        w.y = bf16rne(a.z) | (bf16rne(a.w) << 16);
        w.z = bf16rne(b.x) | (bf16rne(b.y) << 16);
        w.w = bf16rne(b.z) | (bf16rne(b.w) << 16);
        sK[si * 8 + (u ^ (si & 7))] = w;
    }
    __syncthreads();

    // ---- MFMA band compute: wave wv owns 16-row tile ib = i0 + 16*wv
    {
        const int wv = t >> 6, l = t & 63;
        const int ib = i0 + 16 * wv;
        const int m  = l & 15, g = l >> 4;

        // A-fragments straight from global Q (fp32 -> bf16), d = 8g.. / 32+8g..
        s16x8 A1, A2;
        {
            const size_t qb = (size_t)(ib + m) * D4;
            const f4 qa = Q4[qb + 2 * g];
            const f4 qv = Q4[qb + 2 * g + 1];
            const f4 qc = Q4[qb + 8 + 2 * g];
            const f4 qd = Q4[qb + 8 + 2 * g + 1];
            u32x4 wa, wb;
            wa.x = bf16rne(qa.x) | (bf16rne(qa.y) << 16);
            wa.y = bf16rne(qa.z) | (bf16rne(qa.w) << 16);
            wa.z = bf16rne(qv.x) | (bf16rne(qv.y) << 16);
            wa.w = bf16rne(qv.z) | (bf16rne(qv.w) << 16);
            wb.x = bf16rne(qc.x) | (bf16rne(qc.y) << 16);
            wb.y = bf16rne(qc.z) | (bf16rne(qc.w) << 16);
            wb.z = bf16rne(qd.x) | (bf16rne(qd.y) << 16);
            wb.w = bf16rne(qd.z) | (bf16rne(qd.w) << 16);
            A1 = __builtin_bit_cast(s16x8, wa);
            A2 = __builtin_bit_cast(s16x8, wb);
        }

        const int c_lo  = (ib < RAD) ? ((RAD - ib) >> 4) : 0;       // skip j<0 tiles
        const int c_hi0 = (2176 - ib) >> 4;                         // skip j>=2048 tiles
        const int c_hi  = c_hi0 < 17 ? c_hi0 : 17;
        for (int c = c_lo; c < c_hi; ++c) {
            const int si = 16 * (wv + c) + m;                       // staged K row for col j
            const u32x4 b1 = sK[si * 8 + ((g    ) ^ (si & 7))];
            const u32x4 b2 = sK[si * 8 + ((4 + g) ^ (si & 7))];
            f32x4 acc = {0.f, 0.f, 0.f, 0.f};
            acc = __builtin_amdgcn_mfma_f32_16x16x32_bf16(A1, __builtin_bit_cast(s16x8, b1), acc, 0, 0, 0);
            acc = __builtin_amdgcn_mfma_f32_16x16x32_bf16(A2, __builtin_bit_cast(s16x8, b2), acc, 0, 0, 0);
            const int j = ib - RAD + 16 * c + m;                    // C col = lane&15
#pragma unroll
            for (int r = 0; r < 4; ++r) {
                const int i = ib + 4 * g + r;                       // C row = 4*(lane>>4)+reg
                const float v = ((unsigned)(i - j + RAD) <= 2u * RAD) ? acc[r] : 0.f;
                ob[(size_t)i * L_SEQ + j] = v;
            }
        }
    }

    // ---- zero streaming (all waves): complement of each row-tile's window
    {
        f4* O4 = reinterpret_cast<f4*>(ob);
        const f4 zero4 = {0.f, 0.f, 0.f, 0.f};
#pragma unroll 4
        for (int r = 0; r < TI; ++r) {
            const int i   = i0 + r;
            const int ibt = i0 + (r & ~15);                         // row-tile base
            const int wlo = (ibt > RAD ? ibt - RAD : 0) >> 2;
            const int whe = ibt + 144;
            const int whi = (whe < L_SEQ ? whe : L_SEQ) >> 2;
            const int wid = whi - wlo;                              // 36..68 chunks
            const int nz  = NC4 - wid;                              // 444..476
            f4* rowp = O4 + (size_t)i * NC4;
            const int jA = t < wlo ? t : t + wid;
            rowp[jA] = zero4;
            const int z = t + 256;
            if (z < nz) {
                const int jB = z < wlo ? z : z + wid;
                rowp[jB] = zero4;
            }
        }
    }
}

extern "C" void kernel_launch(void* const* d_in, const int* in_sizes, int n_in,
                              void* d_out, int out_size, void* d_ws, size_t ws_size,
                              hipStream_t stream) {
    const float* Q = (const float*)d_in[0];
    const float* K = (const float*)d_in[1];
    float* out = (float*)d_out;
    band_mfma<<<NBLK, 256, 0, stream>>>(Q, K, out);
}

// Round 11
// 195.582 us; speedup vs baseline: 1.0677x; 1.0677x over previous
//
#include <hip/hip_runtime.h>

typedef float  f4    __attribute__((ext_vector_type(4)));
typedef float  f32x4 __attribute__((ext_vector_type(4)));
typedef short  s16x8 __attribute__((ext_vector_type(8)));
typedef unsigned int u32x4 __attribute__((ext_vector_type(4)));

#define L_SEQ 2048
#define D4    16
#define NC4   512
#define RAD   128
#define NBH   48

// Shared coverage contract (HW-validated in R10 where both roles passed in
// one kernel): for each 16-aligned row-tile base ibt, the band kernel writes
// columns [max(0, ibt-128), min(2048, ibt+144)) of every row in the tile
// (band-mask zeros for spares); the zero kernel writes the exact chunk
// complement of that window. Disjoint and exhaustive.

__device__ __forceinline__ unsigned bf16rne(float f) {
    unsigned u = __float_as_uint(f);
    return (u + 0x7FFFu + ((u >> 16) & 1u)) >> 16;   // round-to-nearest-even
}

// ---------------- Kernel Z: pure streaming zero-fill of the complement ----------------
#define ZROWS 16
#define ZBLK  (NBH * (L_SEQ / ZROWS))   // 6144

__global__ __launch_bounds__(256)
void zero_oob(float* __restrict__ outg)
{
    const int t  = threadIdx.x;
    const int id = blockIdx.x;
    const int bh = id >> 7;
    const int r0 = (id & 127) * ZROWS;          // 16-aligned row-tile base
    f4* __restrict__ O4 = reinterpret_cast<f4*>(outg) + (size_t)bh * L_SEQ * NC4;

    // window of this row-tile, in chunks (constant over the 16 rows)
    const int wlo = (r0 > RAD ? r0 - RAD : 0) >> 2;
    const int whe = r0 + 144;
    const int whi = (whe < L_SEQ ? whe : L_SEQ) >> 2;
    const int wid = whi - wlo;                  // 36..68
    const int nz  = NC4 - wid;                  // 444..476 zero chunks per row

    const int  jA  = t < wlo ? t : t + wid;     // t in [0,256) < nz always
    const int  z2  = t + 256;
    const int  jB  = z2 < wlo ? z2 : z2 + wid;
    const bool doB = z2 < nz;
    const f4 zero4 = {0.f, 0.f, 0.f, 0.f};

#pragma unroll
    for (int r = 0; r < ZROWS; ++r) {
        f4* rowp = O4 + (size_t)(r0 + r) * NC4;
        rowp[jA] = zero4;
        if (doB) rowp[jB] = zero4;
    }
}

// ---------------- Kernel B: MFMA band compute (R10-proven) ----------------
#define TI    64             // rows per block (4 waves x 16-row MFMA tiles)
#define NTIL  (L_SEQ / TI)   // 32
#define BBLK  (NBH * NTIL)   // 1536
#define KROWS (TI + 2*RAD)   // 320 staged K rows

__global__ __launch_bounds__(256, 4)
void band_mfma(const float* __restrict__ Qg, const float* __restrict__ Kg,
               float* __restrict__ outg)
{
    // K rows as 8 16B-units (8 bf16, d-ascending); slot = si*8 + (u ^ (si&7))
    // -> staging writes and 16-lane B-frag reads both conflict-free.
    __shared__ u32x4 sK[KROWS * 8];     // 40960 B -> 4 blocks/CU

    const int t  = threadIdx.x;
    const int id = blockIdx.x;
    // bijective XCD swizzle (BBLK % 8 == 0)
    const int swz = (id & 7) * (BBLK / 8) + (id >> 3);
    const int bh  = swz >> 5;
    const int i0  = (swz & (NTIL - 1)) * TI;

    const f4* __restrict__ K4 = reinterpret_cast<const f4*>(Kg) + (size_t)bh * L_SEQ * D4;
    const f4* __restrict__ Q4 = reinterpret_cast<const f4*>(Qg) + (size_t)bh * L_SEQ * D4;
    float* __restrict__ ob    = outg + (size_t)bh * L_SEQ * L_SEQ;

    const int kbase = i0 - RAD;

    // ---- stage K as bf16: 2560 units, 10 per thread
#pragma unroll 2
    for (int itr = 0; itr < 10; ++itr) {
        const int s  = itr * 256 + t;
        const int si = s >> 3, u = s & 7;
        int row = kbase + si;
        row = row < 0 ? 0 : (row > L_SEQ - 1 ? L_SEQ - 1 : row);  // clamp; never read (c-range guards)
        const f4 a = K4[(size_t)row * D4 + 2 * u];
        const f4 b = K4[(size_t)row * D4 + 2 * u + 1];
        u32x4 w;
        w.x = bf16rne(a.x) | (bf16rne(a.y) << 16);
        w.y = bf16rne(a.z) | (bf16rne(a.w) << 16);
        w.z = bf16rne(b.x) | (bf16rne(b.y) << 16);
        w.w = bf16rne(b.z) | (bf16rne(b.w) << 16);
        sK[si * 8 + (u ^ (si & 7))] = w;
    }
    __syncthreads();

    // ---- MFMA band compute: wave wv owns 16-row tile ib = i0 + 16*wv
    {
        const int wv = t >> 6, l = t & 63;
        const int ib = i0 + 16 * wv;
        const int m  = l & 15, g = l >> 4;

        // A-fragments straight from global Q (fp32 -> bf16), d = 8g.. / 32+8g..
        s16x8 A1, A2;
        {
            const size_t qb = (size_t)(ib + m) * D4;
            const f4 qa = Q4[qb + 2 * g];
            const f4 qv = Q4[qb + 2 * g + 1];
            const f4 qc = Q4[qb + 8 + 2 * g];
            const f4 qd = Q4[qb + 8 + 2 * g + 1];
            u32x4 wa, wb;
            wa.x = bf16rne(qa.x) | (bf16rne(qa.y) << 16);
            wa.y = bf16rne(qa.z) | (bf16rne(qa.w) << 16);
            wa.z = bf16rne(qv.x) | (bf16rne(qv.y) << 16);
            wa.w = bf16rne(qv.z) | (bf16rne(qv.w) << 16);
            wb.x = bf16rne(qc.x) | (bf16rne(qc.y) << 16);
            wb.y = bf16rne(qc.z) | (bf16rne(qc.w) << 16);
            wb.z = bf16rne(qd.x) | (bf16rne(qd.y) << 16);
            wb.w = bf16rne(qd.z) | (bf16rne(qd.w) << 16);
            A1 = __builtin_bit_cast(s16x8, wa);
            A2 = __builtin_bit_cast(s16x8, wb);
        }

        const int c_lo  = (ib < RAD) ? ((RAD - ib) >> 4) : 0;       // skip j<0 tiles
        const int c_hi0 = (2176 - ib) >> 4;                         // skip j>=2048 tiles
        const int c_hi  = c_hi0 < 17 ? c_hi0 : 17;
        for (int c = c_lo; c < c_hi; ++c) {
            const int si = 16 * (wv + c) + m;                       // staged K row for col j
            const u32x4 b1 = sK[si * 8 + ((g    ) ^ (si & 7))];
            const u32x4 b2 = sK[si * 8 + ((4 + g) ^ (si & 7))];
            f32x4 acc = {0.f, 0.f, 0.f, 0.f};
            acc = __builtin_amdgcn_mfma_f32_16x16x32_bf16(A1, __builtin_bit_cast(s16x8, b1), acc, 0, 0, 0);
            acc = __builtin_amdgcn_mfma_f32_16x16x32_bf16(A2, __builtin_bit_cast(s16x8, b2), acc, 0, 0, 0);
            const int j = ib - RAD + 16 * c + m;                    // C col = lane&15
#pragma unroll
            for (int r = 0; r < 4; ++r) {
                const int i = ib + 4 * g + r;                       // C row = 4*(lane>>4)+reg
                const float v = ((unsigned)(i - j + RAD) <= 2u * RAD) ? acc[r] : 0.f;
                ob[(size_t)i * L_SEQ + j] = v;
            }
        }
    }
}

extern "C" void kernel_launch(void* const* d_in, const int* in_sizes, int n_in,
                              void* d_out, int out_size, void* d_ws, size_t ws_size,
                              hipStream_t stream) {
    const float* Q = (const float*)d_in[0];
    const float* K = (const float*)d_in[1];
    float* out = (float*)d_out;
    zero_oob<<<ZBLK, 256, 0, stream>>>(out);
    band_mfma<<<BBLK, 256, 0, stream>>>(Q, K, out);
}